// Round 7
// baseline (296.970 us; speedup 1.0000x reference)
//
#include <hip/hip_runtime.h>

// GraphSAGE 2-layer. N=40000, E=640000, 128 -> 512 (relu) -> 256.
// Round 14: depth-2 B pipeline. Rounds 9/12/13 landed the GEMM at ~50 us
// across 3 occupancy/traffic configs (MfmaUtil 13-14% in all) -> per-wave
// structural stall: B register double-buffer was only HALF an iteration
// deep (issue-to-use 40-120 cyc < L2 latency ~200-300 cyc) -> every
// half-K-step stalls ~150 cyc. Fix: two named B sets, body covers K=128,
// loads for k+128 issued right after the MFMAs that free the set ->
// issue-to-use = one full body (>L2 latency). All frags named statically
// (no dynamic reg indexing). +32 VGPR accepted: ILP replaces TLP.
// Also: agg1 redesigned -- 4 nodes/block (wave=node), colidx broadcast via
// readlane (SGPR gather bases), no LDS, no barriers.
// prep/CSR/agg2 unchanged (agg2 fabric-bound ~52.6 us, declared ceiling).

#define N_NODES 40000
#define N_EDGES 640000
#define F_IN 128
#define F_HID 512
#define F_OUT 256
#define NB_SCAN 157  // ceil(40000/256)

typedef unsigned short ushort_t;
typedef __attribute__((ext_vector_type(8))) short bf16x8;
typedef __attribute__((ext_vector_type(4))) float floatx4;

__device__ __forceinline__ ushort_t f2bf(float f) {
  union { float f; unsigned int u; } x; x.f = f;
  unsigned int r = (x.u + 0x7FFFu + ((x.u >> 16) & 1u)) >> 16;  // RNE
  return (ushort_t)r;
}
__device__ __forceinline__ float bf2f(ushort_t u) {
  union { unsigned int u; float f; } x; x.u = ((unsigned int)u) << 16;
  return x.f;
}

// ---------------- CSR build (scans + fill) ----------------
__global__ void scanA_kernel(const int* __restrict__ deg, int* __restrict__ bsum) {
  __shared__ int sdata[256];
  int i = blockIdx.x * 256 + threadIdx.x;
  sdata[threadIdx.x] = (i < N_NODES) ? deg[i] : 0;
  __syncthreads();
  #pragma unroll
  for (int off = 128; off > 0; off >>= 1) {
    if (threadIdx.x < off) sdata[threadIdx.x] += sdata[threadIdx.x + off];
    __syncthreads();
  }
  if (threadIdx.x == 0) bsum[blockIdx.x] = sdata[0];
}

__global__ void scanB_kernel(const int* __restrict__ bsum, int* __restrict__ boff) {
  __shared__ int buf[2][256];
  int tid = threadIdx.x;
  int v = (tid < NB_SCAN) ? bsum[tid] : 0;
  buf[0][tid] = v;
  __syncthreads();
  int cur = 0;
  #pragma unroll
  for (int off = 1; off < 256; off <<= 1) {
    int val = buf[cur][tid];
    if (tid >= off) val += buf[cur][tid - off];
    buf[cur ^ 1][tid] = val;
    __syncthreads();
    cur ^= 1;
  }
  if (tid < NB_SCAN) boff[tid] = buf[cur][tid] - v;  // exclusive
}

__global__ void scanC_kernel(const int* __restrict__ deg, const int* __restrict__ boff,
                             int* __restrict__ rowptr, int* __restrict__ cursor) {
  __shared__ int buf[2][256];
  int tid = threadIdx.x;
  int i = blockIdx.x * 256 + tid;
  int v = (i < N_NODES) ? deg[i] : 0;
  buf[0][tid] = v;
  __syncthreads();
  int cur = 0;
  #pragma unroll
  for (int off = 1; off < 256; off <<= 1) {
    int val = buf[cur][tid];
    if (tid >= off) val += buf[cur][tid - off];
    buf[cur ^ 1][tid] = val;
    __syncthreads();
    cur ^= 1;
  }
  if (i < N_NODES) {
    int ex = boff[blockIdx.x] + buf[cur][tid] - v;
    rowptr[i] = ex;
    cursor[i] = ex;
    if (i == N_NODES - 1) rowptr[N_NODES] = ex + v;  // == E
  }
}

__global__ void fill_kernel(const int* __restrict__ ei, int* __restrict__ cursor,
                            int* __restrict__ col) {
  int e = blockIdx.x * blockDim.x + threadIdx.x;
  if (e < N_EDGES) {
    int d = ei[N_EDGES + e];
    int s = ei[e];
    int pos = atomicAdd(&cursor[d], 1);
    col[pos] = s;
  }
}

// ---------------- fused preprocessing ----------------
// Wp pack: element (n_global = rowoff+n, k_global = koff+k) at
//   Wp[((gg*(KT/32) + t)*4 + ni)*512 + (qk*16 + lm)*8 + j]
// gg=n>>6, ni=(n>>4)&3, lm=n&15, c=kg>>3, t=c>>2, qk=c&3, j=kg&7.
__device__ __forceinline__ void wp_body(const float* __restrict__ W,
                                        ushort_t* __restrict__ Wp,
                                        int i, int K, int N, int rowoff, int koff,
                                        int KT) {
  if (i < K * N) {
    int n = i / K, k = i - n * K;
    int ng = rowoff + n, kg = koff + k;
    int gg = ng >> 6, ni = (ng >> 4) & 3, lm = ng & 15;
    int c = kg >> 3, j = kg & 7, t = c >> 2, qk = c & 3;
    size_t dst = (((size_t)(gg * (KT / 32) + t) * 4 + ni) * 64 + qk * 16 + lm) * 8 + j;
    Wp[dst] = f2bf(W[(size_t)k * N + n]);
  }
}

// block ranges: [0,5000) cvt_x | [5000,5256) W1l | [5256,5512) W1r
// [5512,6024) W2l | [6024,6536) W2r | [6536,6538) biascat | [6538,9038) deg
#define PREP_BLOCKS 9038
__global__ void prep_kernel(const float* __restrict__ x, ushort_t* __restrict__ xb,
                            const float* __restrict__ W1l, const float* __restrict__ W1r,
                            const float* __restrict__ W2l, const float* __restrict__ W2r,
                            ushort_t* __restrict__ Wp1, ushort_t* __restrict__ Wp2,
                            const float* __restrict__ b2, float* __restrict__ bc,
                            const int* __restrict__ ei, int* __restrict__ deg) {
  int b = blockIdx.x, tid = threadIdx.x;
  if (b < 5000) {
    int i = b * 256 + tid;  // per float4
    const int n4 = (N_NODES * F_IN) / 4;
    if (i < n4) {
      float4 v = ((const float4*)x)[i];
      ushort4 o;
      o.x = f2bf(v.x); o.y = f2bf(v.y); o.z = f2bf(v.z); o.w = f2bf(v.w);
      ((ushort4*)xb)[i] = o;
    }
  } else if (b < 5256) {
    wp_body(W1l, Wp1, (b - 5000) * 256 + tid, 128, 512, 0, 0, 256);
  } else if (b < 5512) {
    wp_body(W1r, Wp1, (b - 5256) * 256 + tid, 128, 512, 0, 128, 256);
  } else if (b < 6024) {
    wp_body(W2l, Wp2, (b - 5512) * 256 + tid, 512, 256, 0, 0, 512);
  } else if (b < 6536) {
    wp_body(W2r, Wp2, (b - 6024) * 256 + tid, 512, 256, 256, 0, 512);
  } else if (b < 6538) {
    int i = (b - 6536) * 256 + tid;
    if (i < 512) bc[i] = (i < 256) ? 0.f : b2[i - 256];
  } else {
    int e = (b - 6538) * 256 + tid;
    if (e < N_EDGES) atomicAdd(&deg[ei[N_EDGES + e]], 1);
  }
}

// ---------------- aggregation ----------------
// agg1: 4 nodes per 256-thread block, wave = node. colidx read coalesced
// into a lane register, neighbor ids broadcast via readlane -> SGPR gather
// bases. No LDS, no barriers. 8 gathers in flight.
__global__ __launch_bounds__(256) void agg1_kernel(
    const ushort_t* __restrict__ Xb, ushort_t* __restrict__ Yb,
    const int* __restrict__ rowptr, const int* __restrict__ colidx) {
  const int wave = threadIdx.x >> 6, lane = threadIdx.x & 63;
  const int n = blockIdx.x * 4 + wave;
  const int s = rowptr[n], e = rowptr[n + 1];
  float s0 = 0.f, s1 = 0.f;
  for (int base = s; base < e; base += 64) {
    int cnt = min(64, e - base);
    int c = (base + lane < e) ? colidx[base + lane] : 0;  // coalesced
    int j = 0;
    for (; j + 8 <= cnt; j += 8) {
      unsigned int v[8];
      #pragma unroll
      for (int u = 0; u < 8; ++u) {
        int col = __builtin_amdgcn_readlane(c, j + u);
        v[u] = *(const unsigned int*)(Xb + (size_t)col * F_IN + 2 * lane);
      }
      #pragma unroll
      for (int u = 0; u < 8; ++u) {
        s0 += bf2f((ushort_t)(v[u] & 0xffffu));
        s1 += bf2f((ushort_t)(v[u] >> 16));
      }
    }
    for (; j < cnt; ++j) {
      int col = __builtin_amdgcn_readlane(c, j);
      unsigned int v = *(const unsigned int*)(Xb + (size_t)col * F_IN + 2 * lane);
      s0 += bf2f((ushort_t)(v & 0xffffu));
      s1 += bf2f((ushort_t)(v >> 16));
    }
  }
  float inv = 1.f / fmaxf((float)(e - s), 1.f);
  unsigned int o = (unsigned int)f2bf(s0 * inv) | ((unsigned int)f2bf(s1 * inv) << 16);
  *(unsigned int*)(Yb + (size_t)n * F_IN + 2 * lane) = o;
}

__global__ void agg2_kernel(const ushort_t* __restrict__ hl, const float* __restrict__ hr,
                            float* __restrict__ out,
                            const int* __restrict__ rowptr, const int* __restrict__ colidx) {
  __shared__ int cols[128];
  int n = blockIdx.x, f = threadIdx.x;
  int s = rowptr[n], e = rowptr[n + 1];
  float2 hrv = *(const float2*)(hr + (size_t)n * F_OUT + 2 * f);  // hoisted stream
  float s0 = 0.f, s1 = 0.f;
  for (int base = s; base < e; base += 128) {
    int cnt = min(128, e - base);
    __syncthreads();
    if (f < cnt) cols[f] = colidx[base + f];
    __syncthreads();
    int j = 0;
    for (; j + 8 <= cnt; j += 8) {  // 8 gathers in flight
      unsigned int v[8];
      #pragma unroll
      for (int u = 0; u < 8; ++u)
        v[u] = *(const unsigned int*)(hl + (size_t)cols[j + u] * F_OUT + 2 * f);
      #pragma unroll
      for (int u = 0; u < 8; ++u) {
        s0 += bf2f((ushort_t)(v[u] & 0xffffu));
        s1 += bf2f((ushort_t)(v[u] >> 16));
      }
    }
    for (; j < cnt; ++j) {
      unsigned int v = *(const unsigned int*)(hl + (size_t)cols[j] * F_OUT + 2 * f);
      s0 += bf2f((ushort_t)(v & 0xffffu));
      s1 += bf2f((ushort_t)(v >> 16));
    }
  }
  float inv = 1.f / fmaxf((float)(e - s), 1.f);
  float2 o;
  o.x = s0 * inv + hrv.x;
  o.y = s1 * inv + hrv.y;
  *(float2*)(out + (size_t)n * F_OUT + 2 * f) = o;
}

// ---------------- bf16 MFMA GEMM, depth-2 B pipeline ----------------
// C[M, 512] = Acat[M, KT] @ Wcat[KT, 512] (+bias)(relu). Acat = [A0 | A1]
// when TWOPAIR (K0 = KT/2 each). Wp pre-packed per-lane (see wp_body).
// BM=32, grid 1250, 512 threads / 8 waves; wave w owns cols w*64..w*64+63.
// Full-K A panel staged once (32 x KT = 16/32 KB LDS, XOR swizzle); ONE
// barrier per block. K-loop body covers K=128 with two named B register
// sets; set for step k+128 is loaded right after the MFMAs that consume it
// at step k -> issue-to-use distance ~1 body > L2 latency (~250 cyc).
// Swapped-operand MFMA: acc = mfma(bv, av, acc) -> lane's 4 acc regs are
// 4 consecutive output cols of one row -> vector epilogue stores.
// SPLITOUT: cols<256 -> Cb bf16 [M][256], cols>=256 -> Cf fp32 [M][256].
template <bool TWOPAIR, bool RELU, bool BIAS, bool OUT_BF16, bool SPLITOUT, int KT>
__global__ __launch_bounds__(512) void gemm_mfma(
    const ushort_t* __restrict__ A0, const ushort_t* __restrict__ A1,
    const ushort_t* __restrict__ Wp, const float* __restrict__ bias,
    float* __restrict__ Cf, ushort_t* __restrict__ Cb, int M) {
  const int NKC = KT / 8;            // 16B chunks per row (32 or 64)
  __shared__ ushort_t Apan[32 * KT]; // kc-major + XOR swizzle
  const int tid = threadIdx.x;
  const int wave = tid >> 6, lane = tid & 63;
  const int lm = lane & 15, qk = lane >> 4;
  const int bm = blockIdx.x * 32;    // 1250 * 32 = 40000 exactly, no tail
  const int K0 = TWOPAIR ? KT / 2 : KT;
  const int K0c = K0 / 8;

  // per-wave B base: wave w == 64-col group gg=w in the packed layout
  const ushort_t* wpg = Wp + (size_t)wave * (KT / 32) * 2048;
#define LDB(t, ni) (*(const bf16x8*)(wpg + ((size_t)((t) * 4 + (ni))) * 512 + lane * 8))

  // ---- stage full A panel: coalesced global read -> swizzled ds_write ----
  #pragma unroll
  for (int q = 0; q < (32 * NKC) / 512; ++q) {
    int c = tid + q * 512;
    int lc = c & (NKC - 1);
    int row = c / NKC;
    const ushort_t* src = (TWOPAIR && lc >= K0c)
        ? A1 + (size_t)(bm + row) * K0 + (lc - K0c) * 8
        : A0 + (size_t)(bm + row) * K0 + lc * 8;
    bf16x8 v = *(const bf16x8*)src;
    size_t off = ((size_t)(lc * 32 + row) * 16) ^ (size_t)((lc & 7) << 4);
    *(bf16x8*)((char*)Apan + off) = v;
  }

  // ---- prologue: fill both B sets (K 0..127) before the barrier ----
  bf16x8 b00 = LDB(0, 0), b01 = LDB(0, 1), b02 = LDB(0, 2), b03 = LDB(0, 3);
  bf16x8 b04 = LDB(1, 0), b05 = LDB(1, 1), b06 = LDB(1, 2), b07 = LDB(1, 3);
  bf16x8 b10 = LDB(2, 0), b11 = LDB(2, 1), b12 = LDB(2, 2), b13 = LDB(2, 3);
  bf16x8 b14 = LDB(3, 0), b15 = LDB(3, 1), b16 = LDB(3, 2), b17 = LDB(3, 3);
  __syncthreads();  // the ONLY barrier: A panel visible

  floatx4 acc[2][4] = {};
// one 32-K step: LDS av reads (swizzled) + 8 MFMA against frags f0..f3
#define MM32(k, f0, f1, f2, f3) do {                                        \
    const int kc_ = (k) / 8 + qk;                                           \
    size_t o0_ = ((size_t)(kc_ * 32 + lm) * 16) ^ (size_t)((kc_ & 7) << 4); \
    size_t o1_ = o0_ ^ (16 * 16);                                           \
    bf16x8 av0_ = *(const bf16x8*)((char*)Apan + o0_);                      \
    bf16x8 av1_ = *(const bf16x8*)((char*)Apan + o1_);                      \
    acc[0][0] = __builtin_amdgcn_mfma_f32_16x16x32_bf16(f0, av0_, acc[0][0], 0, 0, 0); \
    acc[0][1] = __builtin_amdgcn_mfma_f32_16x16x32_bf16(f1, av0_, acc[0][1], 0, 0, 0); \
    acc[0][2] = __builtin_amdgcn_mfma_f32_16x16x32_bf16(f2, av0_, acc[0][2], 0, 0, 0); \
    acc[0][3] = __builtin_amdgcn_mfma_f32_16x16x32_bf16(f3, av0_, acc[0][3], 0, 0, 0); \
    acc[1][0] = __builtin_amdgcn_mfma_f32_16x16x32_bf16(f0, av1_, acc[1][0], 0, 0, 0); \
    acc[1][1] = __builtin_amdgcn_mfma_f32_16x16x32_bf16(f1, av1_, acc[1][1], 0, 0, 0); \
    acc[1][2] = __builtin_amdgcn_mfma_f32_16x16x32_bf16(f2, av1_, acc[1][2], 0, 0, 0); \
    acc[1][3] = __builtin_amdgcn_mfma_f32_16x16x32_bf16(f3, av1_, acc[1][3], 0, 0, 0); \
  } while (0)
  // note: o1_ = o0_ ^ 256 is valid because rows 16..31 differ from rows
  // 0..15 only in bit 8 of the pre-swizzle byte offset (row*16, row+=16)
  // and the XOR swizzle touches only bit 4.

  #pragma unroll 1
  for (int kb = 0; kb < KT; kb += 128) {
    const int t = kb / 32;
    MM32(kb,      b00, b01, b02, b03);
    MM32(kb + 32, b04, b05, b06, b07);
    if (kb + 128 < KT) {  // refill set0 for step kb+128 (uniform branch)
      b00 = LDB(t + 4, 0); b01 = LDB(t + 4, 1); b02 = LDB(t + 4, 2); b03 = LDB(t + 4, 3);
      b04 = LDB(t + 5, 0); b05 = LDB(t + 5, 1); b06 = LDB(t + 5, 2); b07 = LDB(t + 5, 3);
    }
    MM32(kb + 64, b10, b11, b12, b13);
    MM32(kb + 96, b14, b15, b16, b17);
    if (kb + 192 < KT) {  // refill set1 for step kb+192
      b10 = LDB(t + 6, 0); b11 = LDB(t + 6, 1); b12 = LDB(t + 6, 2); b13 = LDB(t + 6, 3);
      b14 = LDB(t + 7, 0); b15 = LDB(t + 7, 1); b16 = LDB(t + 7, 2); b17 = LDB(t + 7, 3);
    }
  }
#undef MM32
#undef LDB

  // ---- epilogue: row = bm + mi*16 + lm, cols = wave*64 + ni*16 + qk*4 ----
  #pragma unroll
  for (int ni = 0; ni < 4; ++ni) {
    int colg = wave * 64 + ni * 16 + qk * 4;
    float4 b4 = {0.f, 0.f, 0.f, 0.f};
    if (BIAS) b4 = *(const float4*)&bias[colg];
    #pragma unroll
    for (int mi = 0; mi < 2; ++mi) {
      int rowg = bm + mi * 16 + lm;
      float v0 = acc[mi][ni][0] + b4.x;
      float v1 = acc[mi][ni][1] + b4.y;
      float v2 = acc[mi][ni][2] + b4.z;
      float v3 = acc[mi][ni][3] + b4.w;
      if (RELU) {
        v0 = fmaxf(v0, 0.f); v1 = fmaxf(v1, 0.f);
        v2 = fmaxf(v2, 0.f); v3 = fmaxf(v3, 0.f);
      }
      if (SPLITOUT) {
        if (colg < 256) {
          ushort4 o = {f2bf(v0), f2bf(v1), f2bf(v2), f2bf(v3)};
          *(ushort4*)&Cb[(size_t)rowg * 256 + colg] = o;
        } else {
          float4 o = {v0, v1, v2, v3};
          *(float4*)&Cf[(size_t)rowg * 256 + (colg - 256)] = o;
        }
      } else if (OUT_BF16) {
        ushort4 o = {f2bf(v0), f2bf(v1), f2bf(v2), f2bf(v3)};
        *(ushort4*)&Cb[(size_t)rowg * 512 + colg] = o;
      } else {
        float4 o = {v0, v1, v2, v3};
        *(float4*)&Cf[(size_t)rowg * 512 + colg] = o;
      }
    }
  }
}

extern "C" void kernel_launch(void* const* d_in, const int* in_sizes, int n_in,
                              void* d_out, int out_size, void* d_ws, size_t ws_size,
                              hipStream_t stream) {
  const float* x = (const float*)d_in[0];
  const int* ei = (const int*)d_in[1];  // int32 per harness, [2][E]
  const float* W1l = (const float*)d_in[2];
  const float* b1 = (const float*)d_in[3];
  const float* W1r = (const float*)d_in[4];
  const float* W2l = (const float*)d_in[5];
  const float* b2 = (const float*)d_in[6];
  const float* W2r = (const float*)d_in[7];
  float* out = (float*)d_out;

  char* ws = (char*)d_ws;
  size_t off = 0;
  auto alloc = [&](size_t bytes) {
    void* p = ws + off;
    off = (off + bytes + 255) & ~(size_t)255;
    return p;
  };
  int* deg = (int*)alloc((size_t)N_NODES * 4);
  int* rowptr = (int*)alloc((size_t)(N_NODES + 1) * 4);
  int* cursor = (int*)alloc((size_t)N_NODES * 4);
  int* col = (int*)alloc((size_t)N_EDGES * 4);
  int* bsum = (int*)alloc((size_t)NB_SCAN * 4);
  int* boff = (int*)alloc((size_t)NB_SCAN * 4);
  ushort_t* x_bf = (ushort_t*)alloc((size_t)N_NODES * F_IN * 2);
  ushort_t* aggx_bf = (ushort_t*)alloc((size_t)N_NODES * F_IN * 2);
  ushort_t* h_bf = (ushort_t*)alloc((size_t)N_NODES * F_HID * 2);
  ushort_t* hl_bf = (ushort_t*)alloc((size_t)N_NODES * F_OUT * 2);  // h@W2l, bf16
  float* hr = (float*)alloc((size_t)N_NODES * F_OUT * 4);           // h@W2r + b2
  ushort_t* Wp1 = (ushort_t*)alloc((size_t)512 * 256 * 2);   // packed [W1l^T|W1r^T]
  ushort_t* Wp2 = (ushort_t*)alloc((size_t)512 * 512 * 2);   // packed [W2l|W2r]
  float* biascat = (float*)alloc(512 * 4);

  // Fused preprocessing: cvt_x + 4x wp + biascat + deg (independent work)
  hipMemsetAsync(deg, 0, (size_t)N_NODES * 4, stream);
  prep_kernel<<<PREP_BLOCKS, 256, 0, stream>>>(
      x, x_bf, W1l, W1r, W2l, W2r, Wp1, Wp2, b2, biascat, ei, deg);

  // CSR build
  scanA_kernel<<<NB_SCAN, 256, 0, stream>>>(deg, bsum);
  scanB_kernel<<<1, 256, 0, stream>>>(bsum, boff);
  scanC_kernel<<<NB_SCAN, 256, 0, stream>>>(deg, boff, rowptr, cursor);
  fill_kernel<<<(N_EDGES + 255) / 256, 256, 0, stream>>>(ei, cursor, col);

  // Layer 1: aggx_bf = mean-agg(x_bf); h_bf = relu([aggx|x] @ [W1l;W1r] + b1)
  agg1_kernel<<<N_NODES / 4, 256, 0, stream>>>(x_bf, aggx_bf, rowptr, col);
  gemm_mfma<true, true, true, true, false, 256>
      <<<1250, 512, 0, stream>>>(
          aggx_bf, x_bf, Wp1, b1, nullptr, h_bf, N_NODES);

  // Layer 2 fused: [hl_bf | hr] = h_bf @ [W2l|W2r] + [0|b2], split outputs
  gemm_mfma<false, false, true, false, true, 512>
      <<<1250, 512, 0, stream>>>(
          h_bf, nullptr, Wp2, biascat, hr, hl_bf, N_NODES);
  // out = mean-agg(hl_bf) + hr
  agg2_kernel<<<N_NODES, 128, 0, stream>>>(hl_bf, hr, out, rowptr, col);
}

// Round 8
// 281.661 us; speedup vs baseline: 1.0544x; 1.0544x over previous
//
#include <hip/hip_runtime.h>

// GraphSAGE 2-layer. N=40000, E=640000, 128 -> 512 (relu) -> 256.
// Round 15: FUSED two-layer GEMM. Rounds 9/12/13/14: four GEMM configs all
// ~50 us, MfmaUtil 13-14% -- because the GEMM is HBM-traffic bound, not
// schedule bound (round-5 PMC: 104 MB at 1.97 TB/s for gemm2). Biggest
// traffic term: h [40000][512] bf16 = 41 MB written by gemm1 and read
// right back by gemm2 (82 MB round-trip). Fix: one kernel per 32-row
// M-tile computes layer 1 into a 32 KB LDS Hpan (bf16, kc-major swizzled
// exactly as the A-reader expects; epilogue cols land on aligned 8-B
// sub-chunks -> ds_write_b64), barrier, then runs layer 2 from LDS.
// -82 MB HBM, -1 launch, -1 inter-kernel drain. LDS 16+32=48 KB.
// Also reverted the neutral depth-2 B pipeline (its +VGPR likely cost a
// resident block): simple bvA/bvB half-iteration double-buffer.
// prep/CSR/agg1(readlane)/agg2 unchanged; agg2 is fetch-bound ~52.6 us.

#define N_NODES 40000
#define N_EDGES 640000
#define F_IN 128
#define F_HID 512
#define F_OUT 256
#define NB_SCAN 157  // ceil(40000/256)

typedef unsigned short ushort_t;
typedef __attribute__((ext_vector_type(8))) short bf16x8;
typedef __attribute__((ext_vector_type(4))) float floatx4;

__device__ __forceinline__ ushort_t f2bf(float f) {
  union { float f; unsigned int u; } x; x.f = f;
  unsigned int r = (x.u + 0x7FFFu + ((x.u >> 16) & 1u)) >> 16;  // RNE
  return (ushort_t)r;
}
__device__ __forceinline__ float bf2f(ushort_t u) {
  union { unsigned int u; float f; } x; x.u = ((unsigned int)u) << 16;
  return x.f;
}

// ---------------- CSR build (scans + fill) ----------------
__global__ void scanA_kernel(const int* __restrict__ deg, int* __restrict__ bsum) {
  __shared__ int sdata[256];
  int i = blockIdx.x * 256 + threadIdx.x;
  sdata[threadIdx.x] = (i < N_NODES) ? deg[i] : 0;
  __syncthreads();
  #pragma unroll
  for (int off = 128; off > 0; off >>= 1) {
    if (threadIdx.x < off) sdata[threadIdx.x] += sdata[threadIdx.x + off];
    __syncthreads();
  }
  if (threadIdx.x == 0) bsum[blockIdx.x] = sdata[0];
}

__global__ void scanB_kernel(const int* __restrict__ bsum, int* __restrict__ boff) {
  __shared__ int buf[2][256];
  int tid = threadIdx.x;
  int v = (tid < NB_SCAN) ? bsum[tid] : 0;
  buf[0][tid] = v;
  __syncthreads();
  int cur = 0;
  #pragma unroll
  for (int off = 1; off < 256; off <<= 1) {
    int val = buf[cur][tid];
    if (tid >= off) val += buf[cur][tid - off];
    buf[cur ^ 1][tid] = val;
    __syncthreads();
    cur ^= 1;
  }
  if (tid < NB_SCAN) boff[tid] = buf[cur][tid] - v;  // exclusive
}

__global__ void scanC_kernel(const int* __restrict__ deg, const int* __restrict__ boff,
                             int* __restrict__ rowptr, int* __restrict__ cursor) {
  __shared__ int buf[2][256];
  int tid = threadIdx.x;
  int i = blockIdx.x * 256 + tid;
  int v = (i < N_NODES) ? deg[i] : 0;
  buf[0][tid] = v;
  __syncthreads();
  int cur = 0;
  #pragma unroll
  for (int off = 1; off < 256; off <<= 1) {
    int val = buf[cur][tid];
    if (tid >= off) val += buf[cur][tid - off];
    buf[cur ^ 1][tid] = val;
    __syncthreads();
    cur ^= 1;
  }
  if (i < N_NODES) {
    int ex = boff[blockIdx.x] + buf[cur][tid] - v;
    rowptr[i] = ex;
    cursor[i] = ex;
    if (i == N_NODES - 1) rowptr[N_NODES] = ex + v;  // == E
  }
}

__global__ void fill_kernel(const int* __restrict__ ei, int* __restrict__ cursor,
                            int* __restrict__ col) {
  int e = blockIdx.x * blockDim.x + threadIdx.x;
  if (e < N_EDGES) {
    int d = ei[N_EDGES + e];
    int s = ei[e];
    int pos = atomicAdd(&cursor[d], 1);
    col[pos] = s;
  }
}

// ---------------- fused preprocessing ----------------
// Wp pack: element (n_global = rowoff+n, k_global = koff+k) at
//   Wp[((gg*(KT/32) + t)*4 + ni)*512 + (qk*16 + lm)*8 + j]
// gg=n>>6, ni=(n>>4)&3, lm=n&15, c=kg>>3, j=kg&7, t=c>>2, qk=c&3.
__device__ __forceinline__ void wp_body(const float* __restrict__ W,
                                        ushort_t* __restrict__ Wp,
                                        int i, int K, int N, int rowoff, int koff,
                                        int KT) {
  if (i < K * N) {
    int n = i / K, k = i - n * K;
    int ng = rowoff + n, kg = koff + k;
    int gg = ng >> 6, ni = (ng >> 4) & 3, lm = ng & 15;
    int c = kg >> 3, j = kg & 7, t = c >> 2, qk = c & 3;
    size_t dst = (((size_t)(gg * (KT / 32) + t) * 4 + ni) * 64 + qk * 16 + lm) * 8 + j;
    Wp[dst] = f2bf(W[(size_t)k * N + n]);
  }
}

// block ranges: [0,5000) cvt_x | [5000,5256) W1l | [5256,5512) W1r
// [5512,6024) W2l | [6024,6536) W2r | [6536,6538) biascat | [6538,9038) deg
#define PREP_BLOCKS 9038
__global__ void prep_kernel(const float* __restrict__ x, ushort_t* __restrict__ xb,
                            const float* __restrict__ W1l, const float* __restrict__ W1r,
                            const float* __restrict__ W2l, const float* __restrict__ W2r,
                            ushort_t* __restrict__ Wp1, ushort_t* __restrict__ Wp2,
                            const float* __restrict__ b2, float* __restrict__ bc,
                            const int* __restrict__ ei, int* __restrict__ deg) {
  int b = blockIdx.x, tid = threadIdx.x;
  if (b < 5000) {
    int i = b * 256 + tid;  // per float4
    const int n4 = (N_NODES * F_IN) / 4;
    if (i < n4) {
      float4 v = ((const float4*)x)[i];
      ushort4 o;
      o.x = f2bf(v.x); o.y = f2bf(v.y); o.z = f2bf(v.z); o.w = f2bf(v.w);
      ((ushort4*)xb)[i] = o;
    }
  } else if (b < 5256) {
    wp_body(W1l, Wp1, (b - 5000) * 256 + tid, 128, 512, 0, 0, 256);
  } else if (b < 5512) {
    wp_body(W1r, Wp1, (b - 5256) * 256 + tid, 128, 512, 0, 128, 256);
  } else if (b < 6024) {
    wp_body(W2l, Wp2, (b - 5512) * 256 + tid, 512, 256, 0, 0, 512);
  } else if (b < 6536) {
    wp_body(W2r, Wp2, (b - 6024) * 256 + tid, 512, 256, 256, 0, 512);
  } else if (b < 6538) {
    int i = (b - 6536) * 256 + tid;
    if (i < 512) bc[i] = (i < 256) ? 0.f : b2[i - 256];
  } else {
    int e = (b - 6538) * 256 + tid;
    if (e < N_EDGES) atomicAdd(&deg[ei[N_EDGES + e]], 1);
  }
}

// ---------------- aggregation ----------------
// agg1: 4 nodes per 256-thread block, wave = node. colidx read coalesced
// into a lane register, neighbor ids broadcast via readlane. No LDS/barriers.
__global__ __launch_bounds__(256) void agg1_kernel(
    const ushort_t* __restrict__ Xb, ushort_t* __restrict__ Yb,
    const int* __restrict__ rowptr, const int* __restrict__ colidx) {
  const int wave = threadIdx.x >> 6, lane = threadIdx.x & 63;
  const int n = blockIdx.x * 4 + wave;
  const int s = rowptr[n], e = rowptr[n + 1];
  float s0 = 0.f, s1 = 0.f;
  for (int base = s; base < e; base += 64) {
    int cnt = min(64, e - base);
    int c = (base + lane < e) ? colidx[base + lane] : 0;  // coalesced
    int j = 0;
    for (; j + 8 <= cnt; j += 8) {
      unsigned int v[8];
      #pragma unroll
      for (int u = 0; u < 8; ++u) {
        int col = __builtin_amdgcn_readlane(c, j + u);
        v[u] = *(const unsigned int*)(Xb + (size_t)col * F_IN + 2 * lane);
      }
      #pragma unroll
      for (int u = 0; u < 8; ++u) {
        s0 += bf2f((ushort_t)(v[u] & 0xffffu));
        s1 += bf2f((ushort_t)(v[u] >> 16));
      }
    }
    for (; j < cnt; ++j) {
      int col = __builtin_amdgcn_readlane(c, j);
      unsigned int v = *(const unsigned int*)(Xb + (size_t)col * F_IN + 2 * lane);
      s0 += bf2f((ushort_t)(v & 0xffffu));
      s1 += bf2f((ushort_t)(v >> 16));
    }
  }
  float inv = 1.f / fmaxf((float)(e - s), 1.f);
  unsigned int o = (unsigned int)f2bf(s0 * inv) | ((unsigned int)f2bf(s1 * inv) << 16);
  *(unsigned int*)(Yb + (size_t)n * F_IN + 2 * lane) = o;
}

__global__ void agg2_kernel(const ushort_t* __restrict__ hl, const float* __restrict__ hr,
                            float* __restrict__ out,
                            const int* __restrict__ rowptr, const int* __restrict__ colidx) {
  __shared__ int cols[128];
  int n = blockIdx.x, f = threadIdx.x;
  int s = rowptr[n], e = rowptr[n + 1];
  float2 hrv = *(const float2*)(hr + (size_t)n * F_OUT + 2 * f);  // hoisted stream
  float s0 = 0.f, s1 = 0.f;
  for (int base = s; base < e; base += 128) {
    int cnt = min(128, e - base);
    __syncthreads();
    if (f < cnt) cols[f] = colidx[base + f];
    __syncthreads();
    int j = 0;
    for (; j + 8 <= cnt; j += 8) {  // 8 gathers in flight
      unsigned int v[8];
      #pragma unroll
      for (int u = 0; u < 8; ++u)
        v[u] = *(const unsigned int*)(hl + (size_t)cols[j + u] * F_OUT + 2 * f);
      #pragma unroll
      for (int u = 0; u < 8; ++u) {
        s0 += bf2f((ushort_t)(v[u] & 0xffffu));
        s1 += bf2f((ushort_t)(v[u] >> 16));
      }
    }
    for (; j < cnt; ++j) {
      unsigned int v = *(const unsigned int*)(hl + (size_t)cols[j] * F_OUT + 2 * f);
      s0 += bf2f((ushort_t)(v & 0xffffu));
      s1 += bf2f((ushort_t)(v >> 16));
    }
  }
  float inv = 1.f / fmaxf((float)(e - s), 1.f);
  float2 o;
  o.x = s0 * inv + hrv.x;
  o.y = s1 * inv + hrv.y;
  *(float2*)(out + (size_t)n * F_OUT + 2 * f) = o;
}

// ---------------- fused two-layer bf16 MFMA GEMM ----------------
// Per 32-row M-tile (grid 1250, 512 threads / 8 waves, wave w owns cols
// w*64..w*64+63 of the 512-wide output of each layer):
//   stage [aggx|x] panel (16 KB LDS, kc-major + XOR swizzle)
//   K-loop 1 (KT=256, Wp1) -> acc1
//   epilogue 1: relu(acc1+b1) -> bf16 -> Hpan LDS (32 KB, same swizzled
//     layout the A-reader expects; cols land on aligned 8-B sub-chunks)
//   barrier; K-loop 2 (KT=512, A = Hpan, Wp2) -> acc2
//   epilogue 2: cols<256 -> hl bf16, cols>=256 -> hr fp32 (+biascat)
// B: register double-buffer (bvA/bvB), coalesced 1 KB wave-loads from the
// packed per-lane weight layout; no barriers inside K-loops (2 total).
__device__ __forceinline__ void mm32(const ushort_t* Apan, int k, int qk, int lm,
                                     bf16x8 f0, bf16x8 f1, bf16x8 f2, bf16x8 f3,
                                     floatx4 (&acc)[2][4]) {
  const int kc = k / 8 + qk;
  size_t o0 = ((size_t)(kc * 32 + lm) * 16) ^ (size_t)((kc & 7) << 4);
  bf16x8 av0 = *(const bf16x8*)((const char*)Apan + o0);
  bf16x8 av1 = *(const bf16x8*)((const char*)Apan + (o0 ^ 256));  // rows 16..31
  acc[0][0] = __builtin_amdgcn_mfma_f32_16x16x32_bf16(f0, av0, acc[0][0], 0, 0, 0);
  acc[0][1] = __builtin_amdgcn_mfma_f32_16x16x32_bf16(f1, av0, acc[0][1], 0, 0, 0);
  acc[0][2] = __builtin_amdgcn_mfma_f32_16x16x32_bf16(f2, av0, acc[0][2], 0, 0, 0);
  acc[0][3] = __builtin_amdgcn_mfma_f32_16x16x32_bf16(f3, av0, acc[0][3], 0, 0, 0);
  acc[1][0] = __builtin_amdgcn_mfma_f32_16x16x32_bf16(f0, av1, acc[1][0], 0, 0, 0);
  acc[1][1] = __builtin_amdgcn_mfma_f32_16x16x32_bf16(f1, av1, acc[1][1], 0, 0, 0);
  acc[1][2] = __builtin_amdgcn_mfma_f32_16x16x32_bf16(f2, av1, acc[1][2], 0, 0, 0);
  acc[1][3] = __builtin_amdgcn_mfma_f32_16x16x32_bf16(f3, av1, acc[1][3], 0, 0, 0);
}

__global__ __launch_bounds__(512) void gemm_fused(
    const ushort_t* __restrict__ A0,   // aggx  [40000][128]
    const ushort_t* __restrict__ A1,   // x     [40000][128]
    const ushort_t* __restrict__ Wp1,  // packed layer-1 weights (KT=256)
    const float* __restrict__ b1,
    const ushort_t* __restrict__ Wp2,  // packed layer-2 weights (KT=512)
    const float* __restrict__ bc,      // [0 | b2]
    float* __restrict__ hr, ushort_t* __restrict__ hl) {
  __shared__ ushort_t Apan[32 * 256];  // 16 KB
  __shared__ ushort_t Hpan[32 * 512];  // 32 KB
  const int tid = threadIdx.x;
  const int wave = tid >> 6, lane = tid & 63;
  const int lm = lane & 15, qk = lane >> 4;
  const int bm = blockIdx.x * 32;      // 1250 * 32 = 40000, no tail

  const ushort_t* wpg1 = Wp1 + (size_t)wave * 8 * 2048;   // (256/32) t-blocks
  const ushort_t* wpg2 = Wp2 + (size_t)wave * 16 * 2048;  // (512/32) t-blocks
#define LDB1(t, ni) (*(const bf16x8*)(wpg1 + ((size_t)(t) * 4 + (ni)) * 512 + lane * 8))
#define LDB2(t, ni) (*(const bf16x8*)(wpg2 + ((size_t)(t) * 4 + (ni)) * 512 + lane * 8))

  // ---- stage [aggx|x] panel: 32 rows x 32 chunks, 2 chunks per thread ----
  #pragma unroll
  for (int q = 0; q < 2; ++q) {
    int c = tid + q * 512;
    int lc = c & 31;              // chunk (k / 8)
    int row = c >> 5;
    const ushort_t* src = (lc >= 16)
        ? A1 + (size_t)(bm + row) * 128 + (lc - 16) * 8
        : A0 + (size_t)(bm + row) * 128 + lc * 8;
    bf16x8 v = *(const bf16x8*)src;
    size_t off = ((size_t)(lc * 32 + row) * 16) ^ (size_t)((lc & 7) << 4);
    *(bf16x8*)((char*)Apan + off) = v;
  }

  bf16x8 bvA[4], bvB[4];
  #pragma unroll
  for (int ni = 0; ni < 4; ++ni) bvA[ni] = LDB1(0, ni);
  __syncthreads();  // barrier 1: A panel visible

  // ---- K-loop 1 (KT = 256) ----
  floatx4 acc1[2][4] = {};
  #pragma unroll 1
  for (int kb = 0; kb < 256; kb += 64) {
    const int t0 = kb / 32;
    #pragma unroll
    for (int ni = 0; ni < 4; ++ni) bvB[ni] = LDB1(t0 + 1, ni);
    mm32(Apan, kb, qk, lm, bvA[0], bvA[1], bvA[2], bvA[3], acc1);
    if (kb + 64 < 256) {
      #pragma unroll
      for (int ni = 0; ni < 4; ++ni) bvA[ni] = LDB1(t0 + 2, ni);
    }
    mm32(Apan, kb + 32, qk, lm, bvB[0], bvB[1], bvB[2], bvB[3], acc1);
  }

  // ---- epilogue 1: relu(acc1 + b1) -> bf16 -> Hpan (swizzled) ----
  #pragma unroll
  for (int ni = 0; ni < 4; ++ni) {
    int colg = wave * 64 + ni * 16 + qk * 4;
    float4 b4 = *(const float4*)&b1[colg];
    int lc2 = colg >> 3;
    int sub = (qk & 1) * 8;  // byte offset within the 16-B chunk
    #pragma unroll
    for (int mi = 0; mi < 2; ++mi) {
      int row = mi * 16 + lm;
      ushort4 o;
      o.x = f2bf(fmaxf(acc1[mi][ni][0] + b4.x, 0.f));
      o.y = f2bf(fmaxf(acc1[mi][ni][1] + b4.y, 0.f));
      o.z = f2bf(fmaxf(acc1[mi][ni][2] + b4.z, 0.f));
      o.w = f2bf(fmaxf(acc1[mi][ni][3] + b4.w, 0.f));
      size_t off = (((size_t)(lc2 * 32 + row) * 16) ^ (size_t)((lc2 & 7) << 4)) + sub;
      *(ushort4*)((char*)Hpan + off) = o;
    }
  }

  #pragma unroll
  for (int ni = 0; ni < 4; ++ni) bvA[ni] = LDB2(0, ni);  // issue before barrier
  __syncthreads();  // barrier 2: Hpan visible

  // ---- K-loop 2 (KT = 512, A = Hpan) ----
  floatx4 acc2[2][4] = {};
  #pragma unroll 1
  for (int kb = 0; kb < 512; kb += 64) {
    const int t0 = kb / 32;
    #pragma unroll
    for (int ni = 0; ni < 4; ++ni) bvB[ni] = LDB2(t0 + 1, ni);
    mm32(Hpan, kb, qk, lm, bvA[0], bvA[1], bvA[2], bvA[3], acc2);
    if (kb + 64 < 512) {
      #pragma unroll
      for (int ni = 0; ni < 4; ++ni) bvA[ni] = LDB2(t0 + 2, ni);
    }
    mm32(Hpan, kb + 32, qk, lm, bvB[0], bvB[1], bvB[2], bvB[3], acc2);
  }
#undef LDB1
#undef LDB2

  // ---- epilogue 2: cols<256 -> hl bf16, cols>=256 -> hr fp32 ----
  #pragma unroll
  for (int ni = 0; ni < 4; ++ni) {
    int colg = wave * 64 + ni * 16 + qk * 4;
    float4 b4 = *(const float4*)&bc[colg];
    #pragma unroll
    for (int mi = 0; mi < 2; ++mi) {
      int rowg = bm + mi * 16 + lm;
      float v0 = acc2[mi][ni][0] + b4.x;
      float v1 = acc2[mi][ni][1] + b4.y;
      float v2 = acc2[mi][ni][2] + b4.z;
      float v3 = acc2[mi][ni][3] + b4.w;
      if (colg < 256) {
        ushort4 o = {f2bf(v0), f2bf(v1), f2bf(v2), f2bf(v3)};
        *(ushort4*)&hl[(size_t)rowg * 256 + colg] = o;
      } else {
        float4 o = {v0, v1, v2, v3};
        *(float4*)&hr[(size_t)rowg * 256 + (colg - 256)] = o;
      }
    }
  }
}

extern "C" void kernel_launch(void* const* d_in, const int* in_sizes, int n_in,
                              void* d_out, int out_size, void* d_ws, size_t ws_size,
                              hipStream_t stream) {
  const float* x = (const float*)d_in[0];
  const int* ei = (const int*)d_in[1];  // int32 per harness, [2][E]
  const float* W1l = (const float*)d_in[2];
  const float* b1 = (const float*)d_in[3];
  const float* W1r = (const float*)d_in[4];
  const float* W2l = (const float*)d_in[5];
  const float* b2 = (const float*)d_in[6];
  const float* W2r = (const float*)d_in[7];
  float* out = (float*)d_out;

  char* ws = (char*)d_ws;
  size_t off = 0;
  auto alloc = [&](size_t bytes) {
    void* p = ws + off;
    off = (off + bytes + 255) & ~(size_t)255;
    return p;
  };
  int* deg = (int*)alloc((size_t)N_NODES * 4);
  int* rowptr = (int*)alloc((size_t)(N_NODES + 1) * 4);
  int* cursor = (int*)alloc((size_t)N_NODES * 4);
  int* col = (int*)alloc((size_t)N_EDGES * 4);
  int* bsum = (int*)alloc((size_t)NB_SCAN * 4);
  int* boff = (int*)alloc((size_t)NB_SCAN * 4);
  ushort_t* x_bf = (ushort_t*)alloc((size_t)N_NODES * F_IN * 2);
  ushort_t* aggx_bf = (ushort_t*)alloc((size_t)N_NODES * F_IN * 2);
  ushort_t* hl_bf = (ushort_t*)alloc((size_t)N_NODES * F_OUT * 2);  // h@W2l, bf16
  float* hr = (float*)alloc((size_t)N_NODES * F_OUT * 4);           // h@W2r + b2
  ushort_t* Wp1 = (ushort_t*)alloc((size_t)512 * 256 * 2);   // packed [W1l^T|W1r^T]
  ushort_t* Wp2 = (ushort_t*)alloc((size_t)512 * 512 * 2);   // packed [W2l|W2r]
  float* biascat = (float*)alloc(512 * 4);

  // Fused preprocessing: cvt_x + 4x wp + biascat + deg (independent work)
  hipMemsetAsync(deg, 0, (size_t)N_NODES * 4, stream);
  prep_kernel<<<PREP_BLOCKS, 256, 0, stream>>>(
      x, x_bf, W1l, W1r, W2l, W2r, Wp1, Wp2, b2, biascat, ei, deg);

  // CSR build
  scanA_kernel<<<NB_SCAN, 256, 0, stream>>>(deg, bsum);
  scanB_kernel<<<1, 256, 0, stream>>>(bsum, boff);
  scanC_kernel<<<NB_SCAN, 256, 0, stream>>>(deg, boff, rowptr, cursor);
  fill_kernel<<<(N_EDGES + 255) / 256, 256, 0, stream>>>(ei, cursor, col);

  // Layer 1 aggregation, then fused [layer1 GEMM -> LDS -> layer2 GEMM]
  agg1_kernel<<<N_NODES / 4, 256, 0, stream>>>(x_bf, aggx_bf, rowptr, col);
  gemm_fused<<<1250, 512, 0, stream>>>(
      aggx_bf, x_bf, Wp1, b1, Wp2, biascat, hr, hl_bf);
  // out = mean-agg(hl_bf) + hr
  agg2_kernel<<<N_NODES, 128, 0, stream>>>(hl_bf, hr, out, rowptr, col);
}